// Round 3
// baseline (281.967 us; speedup 1.0000x reference)
//
#include <hip/hip_runtime.h>
#include <hip/hip_bf16.h>
#include <math.h>

// Problem: B=1, N=512, C=256, fp32 in/out.
// out[i,c] = sum_j softmax_j( w[i,j,c] ) * v[j,c],  w = mish(LN(Kp[j]-Qp[i])) @ W2  (+b2 cancels)
// Kp = mish(LN(feat@Wk+bk)) @ W1 + b1 ; Qp = mish(LN(feat@Wq+bq)) @ W1 ; v = feat@Wv+bv
// LN stats of (Kp[j]-Qp[i]) via precomputed row stats + Gram matrix G=Qp·Kp^T:
//   mu_ij = muK[j]-muQ[i];  E[x^2] = (s2K[j]+s2Q[i]-2G[i,j])/C;  var = E[x^2]-mu^2.

#define N_ 512
#define C_ 256

typedef short s4v __attribute__((ext_vector_type(4)));
typedef short s8v __attribute__((ext_vector_type(8)));
typedef float f4v __attribute__((ext_vector_type(4)));

__device__ __forceinline__ unsigned short f2bf(float x) {
  union { __hip_bfloat16 h; unsigned short u; } cv;
  cv.h = __float2bfloat16(x);
  return cv.u;
}

__device__ __forceinline__ float mish_f(float x) {
  // mish(x) = x*tanh(softplus(x)) = x*(y^2-1)/(y^2+1), y = 1+e^x
  if (x > 25.f) return x;  // tanh saturated to 1.0 in fp32
  float y = 1.f + __expf(x);
  float y2 = y * y;
  return x * __fdividef(y2 - 1.f, y2 + 1.f);
}

// block (256 thr) reduction of two values, result broadcast to all threads
__device__ __forceinline__ void blockReduce2(float& a, float& b, float* red) {
  #pragma unroll
  for (int m = 1; m < 64; m <<= 1) { a += __shfl_xor(a, m); b += __shfl_xor(b, m); }
  int lane = threadIdx.x & 63, w = threadIdx.x >> 6;
  if (lane == 0) { red[w] = a; red[4 + w] = b; }
  __syncthreads();
  a = red[0] + red[1] + red[2] + red[3];
  b = red[4] + red[5] + red[6] + red[7];
  __syncthreads();
}

// ---------------- prep: dist, v, Qp, Kp (+row stats, bf16 copies) ----------------
__global__ void __launch_bounds__(256) prep_kernel(
    const float* __restrict__ feat,
    const float* __restrict__ Wq, const float* __restrict__ bq,
    const float* __restrict__ gq, const float* __restrict__ bgq,
    const float* __restrict__ Wk, const float* __restrict__ bk,
    const float* __restrict__ gk, const float* __restrict__ bgk,
    const float* __restrict__ Wv, const float* __restrict__ bv,
    const float* __restrict__ W1, const float* __restrict__ b1,
    float* __restrict__ dist, float* __restrict__ vout,
    float* __restrict__ Qp, float* __restrict__ Kp,
    float* __restrict__ muQ, float* __restrict__ s2Q,
    float* __restrict__ muK, float* __restrict__ s2K,
    unsigned short* __restrict__ Qb, unsigned short* __restrict__ Kb) {
  const int tid = threadIdx.x;
  const int r0 = blockIdx.x * 4;
  __shared__ float fL[4][C_];
  __shared__ float xq[4][C_];
  __shared__ float xk[4][C_];
  __shared__ float red[8];

  #pragma unroll
  for (int r = 0; r < 4; ++r) fL[r][tid] = feat[(r0 + r) * C_ + tid];
  __syncthreads();

  // dist = (sum |feat| > 0)
  {
    float a = fabsf(fL[0][tid]), b = fabsf(fL[1][tid]);
    blockReduce2(a, b, red);
    if (tid == 0) { dist[r0 + 0] = a > 0.f ? 1.f : 0.f; dist[r0 + 1] = b > 0.f ? 1.f : 0.f; }
    a = fabsf(fL[2][tid]); b = fabsf(fL[3][tid]);
    blockReduce2(a, b, red);
    if (tid == 0) { dist[r0 + 2] = a > 0.f ? 1.f : 0.f; dist[r0 + 3] = b > 0.f ? 1.f : 0.f; }
  }

  // q/k/v matmuls (fp32)
  float aq[4] = {0,0,0,0}, ak[4] = {0,0,0,0}, av[4] = {0,0,0,0};
  for (int cp = 0; cp < C_; ++cp) {
    float wq = Wq[cp * C_ + tid], wk = Wk[cp * C_ + tid], wv = Wv[cp * C_ + tid];
    #pragma unroll
    for (int r = 0; r < 4; ++r) {
      float f = fL[r][cp];
      aq[r] += f * wq; ak[r] += f * wk; av[r] += f * wv;
    }
  }
  {
    float bvv = bv[tid];
    #pragma unroll
    for (int r = 0; r < 4; ++r) vout[(r0 + r) * C_ + tid] = av[r] + bvv;
  }

  const float bqv = bq[tid], bkv = bk[tid];
  const float gqv = gq[tid], bgqv = bgq[tid], gkv = gk[tid], bgkv = bgk[tid];
  for (int r = 0; r < 4; ++r) {
    float qv = aq[r] + bqv, kv = ak[r] + bkv;
    float s1 = qv, s2 = qv * qv;
    blockReduce2(s1, s2, red);
    float mu = s1 * (1.f / C_);
    float rs = rsqrtf(s2 * (1.f / C_) - mu * mu + 1e-5f);
    xq[r][tid] = mish_f((qv - mu) * rs * gqv + bgqv);
    s1 = kv; s2 = kv * kv;
    blockReduce2(s1, s2, red);
    mu = s1 * (1.f / C_);
    rs = rsqrtf(s2 * (1.f / C_) - mu * mu + 1e-5f);
    xk[r][tid] = mish_f((kv - mu) * rs * gkv + bgkv);
  }
  __syncthreads();

  // Qp = q@W1, Kp = k@W1 + b1
  float pq[4] = {0,0,0,0}, pk[4] = {0,0,0,0};
  for (int cp = 0; cp < C_; ++cp) {
    float w1 = W1[cp * C_ + tid];
    #pragma unroll
    for (int r = 0; r < 4; ++r) { pq[r] += xq[r][cp] * w1; pk[r] += xk[r][cp] * w1; }
  }
  const float b1v = b1[tid];
  for (int r = 0; r < 4; ++r) {
    float qv2 = pq[r];
    float kv2 = pk[r] + b1v;
    Qp[(r0 + r) * C_ + tid] = qv2;
    Kp[(r0 + r) * C_ + tid] = kv2;
    Qb[(r0 + r) * C_ + tid] = f2bf(qv2);
    Kb[(r0 + r) * C_ + tid] = f2bf(kv2);
    float s1 = qv2, s2 = qv2 * qv2;
    blockReduce2(s1, s2, red);
    if (tid == 0) { muQ[r0 + r] = s1 * (1.f / C_); s2Q[r0 + r] = s2; }
    s1 = kv2; s2 = kv2 * kv2;
    blockReduce2(s1, s2, red);
    if (tid == 0) { muK[r0 + r] = s1 * (1.f / C_); s2K[r0 + r] = s2; }
  }
}

// ---------------- W2 -> bf16 fragment-linear repack ----------------
// W2f[((c16*8+ks)*64+lane)*8+h] = bf16( W2[k][c] ),
//   k = ks*32 + 16*(h>>2) + 4*(lane>>4) + (h&3),  c = c16*16 + (lane&15)
__global__ void __launch_bounds__(256) repack_kernel(
    const float* __restrict__ W2, unsigned short* __restrict__ W2f) {
  int idx = blockIdx.x * 256 + threadIdx.x;  // 65536 total
  int h = idx & 7;
  int l = (idx >> 3) & 63;
  int ks = (idx >> 9) & 7;
  int c16 = idx >> 12;
  int k = ks * 32 + ((h >> 2) << 4) + ((l >> 4) << 2) + (h & 3);
  int c = (c16 << 4) + (l & 15);
  W2f[idx] = f2bf(W2[k * C_ + c]);
}

// ---------------- G = Qp @ Kp^T (bf16 MFMA, fp32 out) ----------------
__global__ void __launch_bounds__(256) gemmG_kernel(
    const unsigned short* __restrict__ Qb, const unsigned short* __restrict__ Kb,
    float* __restrict__ G) {
  const int tid = threadIdx.x;
  const int lane = tid & 63, wave = tid >> 6;
  const int bi = blockIdx.x >> 4, bj = blockIdx.x & 15;
  const int i0 = bi * 32 + (wave >> 1) * 16;
  const int j0 = bj * 32 + (wave & 1) * 16;
  const int jr = lane & 15, kg = lane >> 4;
  const unsigned short* qrow = Qb + (i0 + jr) * C_;
  const unsigned short* krow = Kb + (j0 + jr) * C_;
  f4v acc = (f4v){0.f, 0.f, 0.f, 0.f};
  #pragma unroll
  for (int ks = 0; ks < 8; ++ks) {
    const int kb = ks * 32 + kg * 4;
    s4v alo = *reinterpret_cast<const s4v*>(qrow + kb);
    s4v ahi = *reinterpret_cast<const s4v*>(qrow + kb + 16);
    s4v blo = *reinterpret_cast<const s4v*>(krow + kb);
    s4v bhi = *reinterpret_cast<const s4v*>(krow + kb + 16);
    s8v A, Bv;
    A[0]=alo[0];A[1]=alo[1];A[2]=alo[2];A[3]=alo[3];
    A[4]=ahi[0];A[5]=ahi[1];A[6]=ahi[2];A[7]=ahi[3];
    Bv[0]=blo[0];Bv[1]=blo[1];Bv[2]=blo[2];Bv[3]=blo[3];
    Bv[4]=bhi[0];Bv[5]=bhi[1];Bv[6]=bhi[2];Bv[7]=bhi[3];
    acc = __builtin_amdgcn_mfma_f32_16x16x32_bf16(A, Bv, acc, 0, 0, 0);
  }
  #pragma unroll
  for (int r = 0; r < 4; ++r)
    G[(i0 + kg * 4 + r) * N_ + j0 + jr] = acc[r];
}

// ---------------- main fused kernel ----------------
// 512 blocks (one per i) x 512 threads (8 waves, 32 channels/wave).
// Round-1 phase ordering (tphase -> barrier -> MFMA+softmax -> barrier),
// round-2 math (Gram-trick LN stats, max-free softmax, end-of-loop reduce).
// 8 waves halve per-wave work and cut Bfr to 64 VGPR -> 2 blocks/CU.
__global__ void __launch_bounds__(512, 4) attn_kernel(
    const float* __restrict__ dist, const float* __restrict__ v,
    const float* __restrict__ Qp, const float* __restrict__ Kp,
    const float* __restrict__ muQ, const float* __restrict__ s2Q,
    const float* __restrict__ muK, const float* __restrict__ s2K,
    const float* __restrict__ G, const unsigned short* __restrict__ W2f,
    const float* __restrict__ gw, const float* __restrict__ bw,
    float* __restrict__ out) {
  const int tid = threadIdx.x;
  const int i = blockIdx.x;
  const int lane = tid & 63, wave = tid >> 6;
  const int jg = tid >> 5, g = tid & 31;   // tphase: 16 j-rows x 8 channels
  const int c0 = g * 8;
  const int jr = lane & 15, kg = lane >> 4;
  const int cch = wave * 32 + (lane & 15);

  __shared__ __align__(16) unsigned short T[16 * C_];  // 8 KiB, swizzled

  const float dist_i = dist[i];
  const float muQ_i = muQ[i], s2Q_i = s2Q[i];
  const float* __restrict__ Grow = G + i * N_;

  float qpr[8], gwr[8], bwr[8];
  {
    const float* qprow = Qp + i * C_ + c0;
    #pragma unroll
    for (int e = 0; e < 8; ++e) {
      qpr[e] = qprow[e];
      gwr[e] = gw[c0 + e];
      bwr[e] = bw[c0 + e];
    }
  }

  // resident B fragments: 2 ctiles x 8 ksteps = 64 VGPR
  s8v Bfr[2][8];
  #pragma unroll
  for (int ct = 0; ct < 2; ++ct)
    #pragma unroll
    for (int ks = 0; ks < 8; ++ks)
      Bfr[ct][ks] = *reinterpret_cast<const s8v*>(
          W2f + ((((((wave * 2 + ct) * 8) + ks) * 64) + lane) << 3));

  float den[2] = {0.f, 0.f}, acc[2] = {0.f, 0.f};

  char* Tb = reinterpret_cast<char*>(T);
  const int ab = jg * 512 + g * 16;
  const int sw = (jg & 7) << 4;
  const int swA = (jr & 7) << 4;

  for (int jt = 0; jt < N_ / 16; ++jt) {
    // ---- T phase: t[j, c0..c0+7] = mish(LN(Kp[j]-Qp[i])) ----
    {
      const int j = jt * 16 + jg;
      float mu = muK[j] - muQ_i;
      float ex2 = (s2K[j] + s2Q_i - 2.f * Grow[j]) * (1.f / C_);
      float rs = rsqrtf(fmaxf(ex2 - mu * mu, 0.f) + 1e-5f);
      const float* kpr = Kp + j * C_ + c0;
      s8v t0;
      #pragma unroll
      for (int e = 0; e < 8; ++e) {
        float xm = kpr[e] - qpr[e] - mu;
        t0[e] = (short)f2bf(mish_f(xm * rs * gwr[e] + bwr[e]));
      }
      *reinterpret_cast<s8v*>(Tb + (ab ^ sw)) = t0;
    }
    __syncthreads();

    // ---- MFMA: w[16 x 256] = T @ W2 (this wave: 2 c-tiles) ----
    f4v w4[2];
    w4[0] = (f4v){0.f, 0.f, 0.f, 0.f};
    w4[1] = (f4v){0.f, 0.f, 0.f, 0.f};
    #pragma unroll
    for (int ks = 0; ks < 8; ++ks) {
      const int b0 = jr * 512 + ks * 64 + kg * 8;
      s4v lo = *reinterpret_cast<const s4v*>(Tb + (b0 ^ swA));
      s4v hi = *reinterpret_cast<const s4v*>(Tb + ((b0 + 32) ^ swA));
      s8v A;
      A[0]=lo[0];A[1]=lo[1];A[2]=lo[2];A[3]=lo[3];
      A[4]=hi[0];A[5]=hi[1];A[6]=hi[2];A[7]=hi[3];
      w4[0] = __builtin_amdgcn_mfma_f32_16x16x32_bf16(A, Bfr[0][ks], w4[0], 0, 0, 0);
      w4[1] = __builtin_amdgcn_mfma_f32_16x16x32_bf16(A, Bfr[1][ks], w4[1], 0, 0, 0);
    }

    // ---- per-lane softmax accumulate (no max, no shuffles) ----
    {
      const int jb = jt * 16 + kg * 4;
      const f4v dv = *reinterpret_cast<const f4v*>(dist + jb);
      const float* vb = v + jb * C_ + cch;
      #pragma unroll
      for (int ct = 0; ct < 2; ++ct) {
        #pragma unroll
        for (int r = 0; r < 4; ++r) {
          float e = __expf(fminf(w4[ct][r], 60.f)) * dv[r];
          den[ct] += e;
          acc[ct] += e * vb[r * C_ + ct * 16];
        }
      }
    }
    __syncthreads();  // protect T before next tile's writes
  }

  // cross-kg reduce once
  #pragma unroll
  for (int ct = 0; ct < 2; ++ct) {
    den[ct] += __shfl_xor(den[ct], 16);
    den[ct] += __shfl_xor(den[ct], 32);
    acc[ct] += __shfl_xor(acc[ct], 16);
    acc[ct] += __shfl_xor(acc[ct], 32);
  }
  if (kg == 0) {
    #pragma unroll
    for (int ct = 0; ct < 2; ++ct) {
      float o = 0.f;
      if (dist_i > 0.f && den[ct] > 0.f) o = acc[ct] / den[ct];
      out[i * C_ + cch + ct * 16] = o;
    }
  }
}

extern "C" void kernel_launch(void* const* d_in, const int* in_sizes, int n_in,
                              void* d_out, int out_size, void* d_ws, size_t ws_size,
                              hipStream_t stream) {
  const float* feat = (const float*)d_in[0];
  const float* Wq   = (const float*)d_in[1];
  const float* bq   = (const float*)d_in[2];
  const float* gq   = (const float*)d_in[3];
  const float* bgq  = (const float*)d_in[4];
  const float* Wk   = (const float*)d_in[5];
  const float* bk   = (const float*)d_in[6];
  const float* gk   = (const float*)d_in[7];
  const float* bgk  = (const float*)d_in[8];
  const float* Wv   = (const float*)d_in[9];
  const float* bv   = (const float*)d_in[10];
  const float* W1   = (const float*)d_in[11];
  const float* b1   = (const float*)d_in[12];
  const float* gw   = (const float*)d_in[13];
  const float* bw   = (const float*)d_in[14];
  const float* W2   = (const float*)d_in[15];
  // d_in[16] = b2 : cancels exactly in the j-softmax, unused.

  char* ws = (char*)d_ws;
  float* dist = (float*)(ws + 0);            // 512 f32
  float* muQ  = (float*)(ws + 2048);         // 512 f32
  float* s2Q  = (float*)(ws + 4096);         // 512 f32
  float* muK  = (float*)(ws + 6144);         // 512 f32
  float* s2K  = (float*)(ws + 8192);         // 512 f32
  float* v    = (float*)(ws + 0x010000);     // 512*256 f32 (512 KB)
  float* Qp   = (float*)(ws + 0x090000);     // 512 KB
  float* Kp   = (float*)(ws + 0x110000);     // 512 KB
  unsigned short* Qb  = (unsigned short*)(ws + 0x190000);  // 256 KB
  unsigned short* Kb  = (unsigned short*)(ws + 0x1D0000);  // 256 KB
  unsigned short* W2f = (unsigned short*)(ws + 0x210000);  // 128 KB
  float* G    = (float*)(ws + 0x230000);     // 512*512 f32 (1 MB)

  hipLaunchKernelGGL(prep_kernel, dim3(128), dim3(256), 0, stream,
                     feat, Wq, bq, gq, bgq, Wk, bk, gk, bgk, Wv, bv, W1, b1,
                     dist, v, Qp, Kp, muQ, s2Q, muK, s2K, Qb, Kb);
  hipLaunchKernelGGL(repack_kernel, dim3(256), dim3(256), 0, stream, W2, W2f);
  hipLaunchKernelGGL(gemmG_kernel, dim3(256), dim3(256), 0, stream, Qb, Kb, G);
  hipLaunchKernelGGL(attn_kernel, dim3(512), dim3(512), 0, stream,
                     dist, v, Qp, Kp, muQ, s2Q, muK, s2K, G, W2f, gw, bw,
                     (float*)d_out);
}

// Round 4
// 156.412 us; speedup vs baseline: 1.8027x; 1.8027x over previous
//
#include <hip/hip_runtime.h>
#include <hip/hip_bf16.h>
#include <math.h>

// Problem: B=1, N=512, C=256, fp32 in/out.
// out[i,c] = sum_j softmax_j( w[i,j,c] ) * v[j,c],  w = mish(LN(Kp[j]-Qp[i])) @ W2  (+b2 cancels)
// Kp = mish(LN(feat@Wk+bk)) @ W1 + b1 ; Qp = mish(LN(feat@Wq+bq)) @ W1 ; v = feat@Wv+bv
// R4: R1's measured-best attn structure, j-split 4 ways across blocks
// (max-free softmax => den/acc linear in j => two-pass reduce).

#define N_ 512
#define C_ 256
#define NCHUNK 4
#define JPB (N_ / NCHUNK)   // 128 j's per block

typedef short s4v __attribute__((ext_vector_type(4)));
typedef short s8v __attribute__((ext_vector_type(8)));
typedef float f4v __attribute__((ext_vector_type(4)));

__device__ __forceinline__ unsigned short f2bf(float x) {
  union { __hip_bfloat16 h; unsigned short u; } cv;
  cv.h = __float2bfloat16(x);
  return cv.u;
}

__device__ __forceinline__ float mish_f(float x) {
  // mish(x) = x*tanh(softplus(x)) = x*(y^2-1)/(y^2+1), y = 1+e^x
  if (x > 25.f) return x;  // tanh saturated to 1.0 in fp32
  float y = 1.f + __expf(x);
  float y2 = y * y;
  return x * __fdividef(y2 - 1.f, y2 + 1.f);
}

// block (256 thr) reduction of two values, result broadcast to all threads
__device__ __forceinline__ void blockReduce2(float& a, float& b, float* red) {
  #pragma unroll
  for (int m = 1; m < 64; m <<= 1) { a += __shfl_xor(a, m); b += __shfl_xor(b, m); }
  int lane = threadIdx.x & 63, w = threadIdx.x >> 6;
  if (lane == 0) { red[w] = a; red[4 + w] = b; }
  __syncthreads();
  a = red[0] + red[1] + red[2] + red[3];
  b = red[4] + red[5] + red[6] + red[7];
  __syncthreads();
}

// ---------------- prep: dist, v, Qp, Kp (fp32) ----------------
__global__ void __launch_bounds__(256) prep_kernel(
    const float* __restrict__ feat,
    const float* __restrict__ Wq, const float* __restrict__ bq,
    const float* __restrict__ gq, const float* __restrict__ bgq,
    const float* __restrict__ Wk, const float* __restrict__ bk,
    const float* __restrict__ gk, const float* __restrict__ bgk,
    const float* __restrict__ Wv, const float* __restrict__ bv,
    const float* __restrict__ W1, const float* __restrict__ b1,
    float* __restrict__ dist, float* __restrict__ vout,
    float* __restrict__ Qp, float* __restrict__ Kp) {
  const int tid = threadIdx.x;
  const int r0 = blockIdx.x * 4;
  __shared__ float fL[4][C_];
  __shared__ float xq[4][C_];
  __shared__ float xk[4][C_];
  __shared__ float red[8];

  #pragma unroll
  for (int r = 0; r < 4; ++r) fL[r][tid] = feat[(r0 + r) * C_ + tid];
  __syncthreads();

  // dist = (sum |feat| > 0)
  {
    float a = fabsf(fL[0][tid]), b = fabsf(fL[1][tid]);
    blockReduce2(a, b, red);
    if (tid == 0) { dist[r0 + 0] = a > 0.f ? 1.f : 0.f; dist[r0 + 1] = b > 0.f ? 1.f : 0.f; }
    a = fabsf(fL[2][tid]); b = fabsf(fL[3][tid]);
    blockReduce2(a, b, red);
    if (tid == 0) { dist[r0 + 2] = a > 0.f ? 1.f : 0.f; dist[r0 + 3] = b > 0.f ? 1.f : 0.f; }
  }

  // q/k/v matmuls (fp32)
  float aq[4] = {0,0,0,0}, ak[4] = {0,0,0,0}, av[4] = {0,0,0,0};
  for (int cp = 0; cp < C_; ++cp) {
    float wq = Wq[cp * C_ + tid], wk = Wk[cp * C_ + tid], wv = Wv[cp * C_ + tid];
    #pragma unroll
    for (int r = 0; r < 4; ++r) {
      float f = fL[r][cp];
      aq[r] += f * wq; ak[r] += f * wk; av[r] += f * wv;
    }
  }
  {
    float bvv = bv[tid];
    #pragma unroll
    for (int r = 0; r < 4; ++r) vout[(r0 + r) * C_ + tid] = av[r] + bvv;
  }

  const float bqv = bq[tid], bkv = bk[tid];
  const float gqv = gq[tid], bgqv = bgq[tid], gkv = gk[tid], bgkv = bgk[tid];
  for (int r = 0; r < 4; ++r) {
    float qv = aq[r] + bqv, kv = ak[r] + bkv;
    float s1 = qv, s2 = qv * qv;
    blockReduce2(s1, s2, red);
    float mu = s1 * (1.f / C_);
    float rs = rsqrtf(s2 * (1.f / C_) - mu * mu + 1e-5f);
    xq[r][tid] = mish_f((qv - mu) * rs * gqv + bgqv);
    s1 = kv; s2 = kv * kv;
    blockReduce2(s1, s2, red);
    mu = s1 * (1.f / C_);
    rs = rsqrtf(s2 * (1.f / C_) - mu * mu + 1e-5f);
    xk[r][tid] = mish_f((kv - mu) * rs * gkv + bgkv);
  }
  __syncthreads();

  // Qp = q@W1, Kp = k@W1 + b1
  float pq[4] = {0,0,0,0}, pk[4] = {0,0,0,0};
  for (int cp = 0; cp < C_; ++cp) {
    float w1 = W1[cp * C_ + tid];
    #pragma unroll
    for (int r = 0; r < 4; ++r) { pq[r] += xq[r][cp] * w1; pk[r] += xk[r][cp] * w1; }
  }
  const float b1v = b1[tid];
  #pragma unroll
  for (int r = 0; r < 4; ++r) {
    Qp[(r0 + r) * C_ + tid] = pq[r];
    Kp[(r0 + r) * C_ + tid] = pk[r] + b1v;
  }
}

// ---------------- W2 -> bf16 fragment-linear repack ----------------
// W2f[((c16*8+ks)*64+lane)*8+h] = bf16( W2[k][c] ),
//   k = ks*32 + 16*(h>>2) + 4*(lane>>4) + (h&3),  c = c16*16 + (lane&15)
__global__ void __launch_bounds__(256) repack_kernel(
    const float* __restrict__ W2, unsigned short* __restrict__ W2f) {
  int idx = blockIdx.x * 256 + threadIdx.x;  // 65536 total
  int h = idx & 7;
  int l = (idx >> 3) & 63;
  int ks = (idx >> 9) & 7;
  int c16 = idx >> 12;
  int k = ks * 32 + ((h >> 2) << 4) + ((l >> 4) << 2) + (h & 3);
  int c = (c16 << 4) + (l & 15);
  W2f[idx] = f2bf(W2[k * C_ + c]);
}

// ---------------- main fused kernel (pass 1 of 2) ----------------
// grid (512, 4): blockIdx.x = i, blockIdx.y = j-chunk (128 j's). 256 thr, 4 waves.
// R1 phase order: tphase -> barrier -> MFMA + max-free softmax accumulate -> barrier.
// Partial den/acc per (chunk, i, c) written to workspace; pass 2 merges.
__global__ void __launch_bounds__(256, 2) attn_kernel(
    const float* __restrict__ dist, const float* __restrict__ v,
    const float* __restrict__ Qp, const float* __restrict__ Kp,
    const unsigned short* __restrict__ W2f,
    const float* __restrict__ gw, const float* __restrict__ bw,
    float* __restrict__ pden, float* __restrict__ pacc) {
  const int tid = threadIdx.x;
  const int i = blockIdx.x;
  const int chunk = blockIdx.y;
  const int j0 = chunk * JPB;
  const int lane = tid & 63, wave = tid >> 6;
  const int jg = tid >> 4;       // local j row this thread computes (T phase)
  const int g = tid & 15;        // sub-group lane
  const int c0 = g * 16;         // T phase channel base (16 channels/thread)
  const int jr = lane & 15;      // MFMA A-fragment row
  const int kg = lane >> 4;      // k-group / D-row group
  const int cch = wave * 64 + (lane & 15);  // softmax channel base (+ct*16)

  __shared__ __align__(16) unsigned short T[16 * C_];  // 8 KiB, swizzled
  __shared__ float distT[16];
  char* Tb = reinterpret_cast<char*>(T);

  // hoisted per-thread constants
  float qpr[16], gwr[16], bwr[16];
  {
    const float* qprow = Qp + i * C_ + c0;
    #pragma unroll
    for (int e = 0; e < 16; ++e) {
      qpr[e] = qprow[e];
      gwr[e] = gw[c0 + e];
      bwr[e] = bw[c0 + e];
    }
  }

  // resident B fragments: 4 ctiles x 8 ksteps
  s8v Bfr[4][8];
  #pragma unroll
  for (int ct = 0; ct < 4; ++ct)
    #pragma unroll
    for (int ks = 0; ks < 8; ++ks)
      Bfr[ct][ks] = *reinterpret_cast<const s8v*>(
          W2f + (((((wave * 4 + ct) * 8 + ks) * 64) + lane) << 3));

  float den[4] = {0.f, 0.f, 0.f, 0.f}, acc[4] = {0.f, 0.f, 0.f, 0.f};

  for (int jt = 0; jt < JPB / 16; ++jt) {
    const int j = j0 + jt * 16 + jg;
    // ---- T phase: t[j, c0..c0+15] = mish(LN(Kp[j]-Qp[i])) ----
    const float* kpr = Kp + j * C_ + c0;
    float d[16];
    float s = 0.f, s2 = 0.f;
    #pragma unroll
    for (int e = 0; e < 16; ++e) {
      float x = kpr[e] - qpr[e];
      d[e] = x; s += x; s2 += x * x;
    }
    #pragma unroll
    for (int mk = 1; mk < 16; mk <<= 1) { s += __shfl_xor(s, mk); s2 += __shfl_xor(s2, mk); }
    float mu = s * (1.f / C_);
    float rs = rsqrtf(s2 * (1.f / C_) - mu * mu + 1e-5f);
    if (g == 0) distT[jg] = dist[j];
    s8v t0, t1;
    #pragma unroll
    for (int e = 0; e < 8; ++e)
      t0[e] = (short)f2bf(mish_f((d[e] - mu) * rs * gwr[e] + bwr[e]));
    #pragma unroll
    for (int e = 8; e < 16; ++e)
      t1[e - 8] = (short)f2bf(mish_f((d[e] - mu) * rs * gwr[e] + bwr[e]));
    const int ab = jg * 512 + g * 32;
    const int sw = (jg & 7) << 4;
    *reinterpret_cast<s8v*>(Tb + (ab ^ sw)) = t0;
    *reinterpret_cast<s8v*>(Tb + ((ab + 16) ^ sw)) = t1;
    __syncthreads();

    // ---- MFMA: w[16 x 256] = T @ W2 ----
    f4v w4[4];
    #pragma unroll
    for (int ct = 0; ct < 4; ++ct) w4[ct] = (f4v){0.f, 0.f, 0.f, 0.f};
    const int swA = (jr & 7) << 4;
    #pragma unroll
    for (int ks = 0; ks < 8; ++ks) {
      // A element h: k = ks*32 + 16*(h>>2) + 4*kg + (h&3)
      const int b0 = jr * 512 + ks * 64 + kg * 8;
      s4v lo = *reinterpret_cast<const s4v*>(Tb + (b0 ^ swA));
      s4v hi = *reinterpret_cast<const s4v*>(Tb + ((b0 + 32) ^ swA));
      s8v A;
      A[0] = lo[0]; A[1] = lo[1]; A[2] = lo[2]; A[3] = lo[3];
      A[4] = hi[0]; A[5] = hi[1]; A[6] = hi[2]; A[7] = hi[3];
      #pragma unroll
      for (int ct = 0; ct < 4; ++ct)
        w4[ct] = __builtin_amdgcn_mfma_f32_16x16x32_bf16(A, Bfr[ct][ks], w4[ct], 0, 0, 0);
    }

    // ---- max-free softmax accumulate (no cross-lane ops) ----
    const int jb = j0 + jt * 16 + kg * 4;
    float dv[4];
    #pragma unroll
    for (int r = 0; r < 4; ++r) dv[r] = distT[kg * 4 + r];
    const float* vb = v + jb * C_;
    #pragma unroll
    for (int ct = 0; ct < 4; ++ct) {
      const int c = cch + ct * 16;
      #pragma unroll
      for (int r = 0; r < 4; ++r) {
        float e = __expf(fminf(w4[ct][r], 60.f)) * dv[r];
        den[ct] += e;
        acc[ct] += e * vb[r * C_ + c];
      }
    }
    __syncthreads();  // protect T before next tile's writes
  }

  // cross-kg reduce once, then write partials
  #pragma unroll
  for (int ct = 0; ct < 4; ++ct) {
    den[ct] += __shfl_xor(den[ct], 16);
    den[ct] += __shfl_xor(den[ct], 32);
    acc[ct] += __shfl_xor(acc[ct], 16);
    acc[ct] += __shfl_xor(acc[ct], 32);
  }
  if (kg == 0) {
    #pragma unroll
    for (int ct = 0; ct < 4; ++ct) {
      const int c = cch + ct * 16;
      pden[(chunk * N_ + i) * C_ + c] = den[ct];
      pacc[(chunk * N_ + i) * C_ + c] = acc[ct];
    }
  }
}

// ---------------- pass 2: merge chunk partials ----------------
__global__ void __launch_bounds__(256) reduce_kernel(
    const float* __restrict__ dist,
    const float* __restrict__ pden, const float* __restrict__ pacc,
    float* __restrict__ out) {
  const int i = blockIdx.x, c = threadIdx.x;
  float den = 0.f, acc = 0.f;
  #pragma unroll
  for (int ch = 0; ch < NCHUNK; ++ch) {
    den += pden[(ch * N_ + i) * C_ + c];
    acc += pacc[(ch * N_ + i) * C_ + c];
  }
  float o = 0.f;
  if (dist[i] > 0.f && den > 0.f) o = acc / den;
  out[i * C_ + c] = o;
}

extern "C" void kernel_launch(void* const* d_in, const int* in_sizes, int n_in,
                              void* d_out, int out_size, void* d_ws, size_t ws_size,
                              hipStream_t stream) {
  const float* feat = (const float*)d_in[0];
  const float* Wq   = (const float*)d_in[1];
  const float* bq   = (const float*)d_in[2];
  const float* gq   = (const float*)d_in[3];
  const float* bgq  = (const float*)d_in[4];
  const float* Wk   = (const float*)d_in[5];
  const float* bk   = (const float*)d_in[6];
  const float* gk   = (const float*)d_in[7];
  const float* bgk  = (const float*)d_in[8];
  const float* Wv   = (const float*)d_in[9];
  const float* bv   = (const float*)d_in[10];
  const float* W1   = (const float*)d_in[11];
  const float* b1   = (const float*)d_in[12];
  const float* gw   = (const float*)d_in[13];
  const float* bw   = (const float*)d_in[14];
  const float* W2   = (const float*)d_in[15];
  // d_in[16] = b2 : cancels exactly in the j-softmax, unused.

  char* ws = (char*)d_ws;
  float* dist = (float*)(ws + 0);            // 512 f32
  float* v    = (float*)(ws + 0x010000);     // 512 KB
  float* Qp   = (float*)(ws + 0x090000);     // 512 KB
  float* Kp   = (float*)(ws + 0x110000);     // 512 KB
  unsigned short* W2f = (unsigned short*)(ws + 0x190000);  // 128 KB
  float* pden = (float*)(ws + 0x1B0000);     // 4*512*256 f32 = 2 MB
  float* pacc = (float*)(ws + 0x3B0000);     // 2 MB

  hipLaunchKernelGGL(prep_kernel, dim3(128), dim3(256), 0, stream,
                     feat, Wq, bq, gq, bgq, Wk, bk, gk, bgk, Wv, bv, W1, b1,
                     dist, v, Qp, Kp);
  hipLaunchKernelGGL(repack_kernel, dim3(256), dim3(256), 0, stream, W2, W2f);
  hipLaunchKernelGGL(attn_kernel, dim3(512, NCHUNK), dim3(256), 0, stream,
                     dist, v, Qp, Kp, W2f, gw, bw, pden, pacc);
  hipLaunchKernelGGL(reduce_kernel, dim3(512), dim3(256), 0, stream,
                     dist, pden, pacc, (float*)d_out);
}